// Round 19
// baseline (961.079 us; speedup 1.0000x reference)
//
#include <hip/hip_runtime.h>
#include <hip/hip_bf16.h>

#define NB 2048
#define NF 6144
#define ND 768
#define BM 256
#define BN 192
#define BK 64
#define SPLITK 2
#define KCH (NF / SPLITK)  // 3072 per block
#define NTIL (KCH / BK)    // 48 K-tiles per block

// LDS: A 256 rows x 128 B = 32 KB; B 192 rows x 128 B = 24 KB; dbuf = 112 KB
#define ABYTES (BM * 128)
#define BBYTES (BN * 128)
#define BUFBYTES (ABYTES + BBYTES)

typedef __attribute__((ext_vector_type(4))) __bf16 bf16x4;
typedef __attribute__((ext_vector_type(8))) __bf16 bf16x8;
typedef __attribute__((ext_vector_type(4))) float f32x4;

// Proven layout (0 conflicts, rounds 2-18): 128B rows of 64 bf16,
// 16B-slot 3-bit swizzle slot = (k>>3) ^ (row&7) ^ ((row>>2)&7)
__device__ __forceinline__ char* lds_addr(char* base, int row, int k) {
  const int blk = ((k >> 3) ^ (row & 7) ^ ((row >> 2) & 7)) & 7;
  return base + row * 128 + (blk << 4) + ((k & 7) << 1);
}

#define SBAR0() __builtin_amdgcn_sched_barrier(0)
#define LGKM0()                                            \
  do {                                                     \
    asm volatile("s_waitcnt lgkmcnt(0)" ::: "memory");     \
    SBAR0();                                               \
  } while (0)

// out[b,d] = sum_l bias[l,d]  (clears 0xAA poison deterministically)
__global__ __launch_bounds__(256) void bias_init_kernel(
    const float* __restrict__ bias, const int* __restrict__ lidx,
    float* __restrict__ out) {
  int n = lidx[0] + 1;
  int i = blockIdx.x * 256 + threadIdx.x;
  if (i >= NB * ND) return;
  int d = i % ND;
  float s = 0.f;
  for (int l = 0; l < n; ++l) s += bias[l * ND + d];
  out[i] = s;
}

// 12-wave variant of the R8 structure: 256x192 tile, 768 threads = 12 waves
// (4m x 3n, wave tile 64x64), BK=64, split-K x2, LDS dbuf, ONE lgkm-only
// barrier per K-tile. Rationale: acc shrinks 96->64 VGPRs (clears the
// register wall that killed R3/R11/R15/R17), 3 waves/SIMD (+50% TLP for
// intra-block pipe overlap), staging not duplicated (unlike multi-block).
// A staging split into two 16-reg chunks (same proven write pattern as R8,
// rows +64 per pass); B staged by all 768 threads (4 float4 -> 4 b64 writes).
__global__ __launch_bounds__(768, 3) void gemm_kernel(
    const float* __restrict__ acts, const float* __restrict__ W,
    const int* __restrict__ lidx, float* __restrict__ out, int nwg) {
  extern __shared__ char cbuf[];  // 2 * BUFBYTES

  // by-fastest decode + XCD swizzle (R8: FETCH 1.27GB -> 405MB)
  const int chunk = nwg >> 3;  // 96
  const int swz = (blockIdx.x & 7) * chunk + (blockIdx.x >> 3);
  const int by = swz & 3;  // id = by + 4*(m + 8*(ks + 2*l))
  int rem = swz >> 2;
  const int m = rem & 7; rem >>= 3;
  const int ks = rem & 1; rem >>= 1;
  const int l = rem;
  if (l > lidx[0]) return;  // uniform exit before any barrier

  const int brow = m * BM;
  const int ncol = by * BN;
  const int k0 = ks * KCH;

  const int tid = threadIdx.x;
  const int lane = tid & 63;
  const int wid = tid >> 6;          // 0..11: 4m x 3n
  const int wrow = (wid / 3) * 64;   // 0,64,128,192
  const int wcol = (wid % 3) * 64;   // 0,64,128

  f32x4 acc[4][4];
#pragma unroll
  for (int i = 0; i < 4; ++i)
#pragma unroll
    for (int j = 0; j < 4; ++j) acc[i][j] = (f32x4){0.f, 0.f, 0.f, 0.f};

  // A staging (waves 0-7, wave-uniform gate): row = tid>>3 (+64 per pass),
  // 8 consecutive k -- byte-identical write pattern to R8 (0 conflicts),
  // split into chunk0 = passes 0,1 and chunk1 = passes 2,3 (16 regs each).
  const bool astage = tid < 512;
  const int s_arow = tid >> 3;        // 0..63
  const int s_ak = (tid & 7) * 8;
  const float* Aptr =
      acts + (size_t)l * NB * NF + (size_t)(brow + s_arow) * NF + k0 + s_ak;
  float4 av0[2][2], av1[2][2];

  // B staging (all 768 threads): 4 consecutive d, 4 consecutive k (16 regs).
  const int s_bd = (tid % 48) * 4;    // 0..188
  const int s_bk = (tid / 48) * 4;    // 0..60
  const float* Bptr =
      W + (size_t)l * NF * ND + (size_t)(k0 + s_bk) * ND + (ncol + s_bd);
  float4 bv[4];

#define ALOADS0(kb)                                                          \
  do {                                                                       \
    if (astage) {                                                            \
      _Pragma("unroll") for (int p = 0; p < 2; ++p) {                        \
        av0[p][0] = *(const float4*)(Aptr + (size_t)(64 * p) * NF + (kb));   \
        av0[p][1] = *(const float4*)(Aptr + (size_t)(64 * p) * NF + (kb) + 4); \
      }                                                                      \
    }                                                                        \
  } while (0)
#define ALOADS1(kb)                                                          \
  do {                                                                       \
    if (astage) {                                                            \
      _Pragma("unroll") for (int p = 0; p < 2; ++p) {                        \
        av1[p][0] = *(const float4*)(Aptr + (size_t)(64 * (2 + p)) * NF + (kb)); \
        av1[p][1] = *(const float4*)(Aptr + (size_t)(64 * (2 + p)) * NF + (kb) + 4); \
      }                                                                      \
    }                                                                        \
  } while (0)
#define ASTORE0(cA_)                                                         \
  do {                                                                       \
    if (astage) {                                                            \
      _Pragma("unroll") for (int p = 0; p < 2; ++p) {                        \
        bf16x8 h;                                                            \
        h[0] = (__bf16)av0[p][0].x; h[1] = (__bf16)av0[p][0].y;              \
        h[2] = (__bf16)av0[p][0].z; h[3] = (__bf16)av0[p][0].w;              \
        h[4] = (__bf16)av0[p][1].x; h[5] = (__bf16)av0[p][1].y;              \
        h[6] = (__bf16)av0[p][1].z; h[7] = (__bf16)av0[p][1].w;              \
        *(bf16x8*)lds_addr((cA_), s_arow + 64 * p, s_ak) = h;                \
      }                                                                      \
    }                                                                        \
  } while (0)
#define ASTORE1(cA_)                                                         \
  do {                                                                       \
    if (astage) {                                                            \
      _Pragma("unroll") for (int p = 0; p < 2; ++p) {                        \
        bf16x8 h;                                                            \
        h[0] = (__bf16)av1[p][0].x; h[1] = (__bf16)av1[p][0].y;              \
        h[2] = (__bf16)av1[p][0].z; h[3] = (__bf16)av1[p][0].w;              \
        h[4] = (__bf16)av1[p][1].x; h[5] = (__bf16)av1[p][1].y;              \
        h[6] = (__bf16)av1[p][1].z; h[7] = (__bf16)av1[p][1].w;              \
        *(bf16x8*)lds_addr((cA_), s_arow + 64 * (2 + p), s_ak) = h;          \
      }                                                                      \
    }                                                                        \
  } while (0)
#define BLOADS(kb)                                                           \
  do {                                                                       \
    _Pragma("unroll") for (int j = 0; j < 4; ++j)                            \
      bv[j] = *(const float4*)(Bptr + (size_t)((kb) + j) * ND);              \
  } while (0)
#define BSTORE(cB_)                                                          \
  do {                                                                       \
    _Pragma("unroll") for (int dd = 0; dd < 4; ++dd) {                       \
      bf16x4 h;                                                              \
      h[0] = (__bf16)bv[0][dd]; h[1] = (__bf16)bv[1][dd];                    \
      h[2] = (__bf16)bv[2][dd]; h[3] = (__bf16)bv[3][dd];                    \
      *(bf16x4*)lds_addr((cB_), s_bd + dd, s_bk) = h;                        \
    }                                                                        \
  } while (0)

// One k-step phase S (0 or 1): read 4 aF + 4 bF fragments (proven patterns),
// lgkm drain, setprio-wrapped 16-MFMA cluster.
#define PHASE(S)                                                             \
  do {                                                                       \
    bf16x8 aF[4], bF[4];                                                     \
    _Pragma("unroll") for (int mi = 0; mi < 4; ++mi)                         \
      aF[mi] = *(const bf16x8*)lds_addr(                                     \
          rA, wrow + mi * 16 + (lane & 15), (S) * 32 + (lane >> 4) * 8);     \
    _Pragma("unroll") for (int ni = 0; ni < 4; ++ni)                         \
      bF[ni] = *(const bf16x8*)lds_addr(                                     \
          rB, wcol + ni * 16 + (lane & 15), (S) * 32 + (lane >> 4) * 8);     \
    LGKM0();                                                                 \
    __builtin_amdgcn_s_setprio(1);                                           \
    _Pragma("unroll") for (int mi = 0; mi < 4; ++mi)                         \
      _Pragma("unroll") for (int ni = 0; ni < 4; ++ni)                       \
        acc[mi][ni] = __builtin_amdgcn_mfma_f32_16x16x32_bf16(               \
            aF[mi], bF[ni], acc[mi][ni], 0, 0, 0);                           \
    __builtin_amdgcn_s_setprio(0);                                           \
    SBAR0();                                                                 \
  } while (0)

  // ---- prologue: tile 0 staged into buf0 (self-waiting, once) ----
  ALOADS0(0); ASTORE0(cbuf);
  ALOADS1(0); ASTORE1(cbuf);
  BLOADS(0);  BSTORE(cbuf + ABYTES);

  for (int t = 0; t < NTIL; ++t) {
    const int cur = t & 1;
    char* rA = cbuf + (size_t)cur * BUFBYTES;
    char* rB = rA + ABYTES;
    char* wA = cbuf + (size_t)(cur ^ 1) * BUFBYTES;
    char* wB = wA + ABYTES;
    const bool more = (t + 1 < NTIL);

    // tile boundary: writes visible + reads done (lgkm drain); vmcnt NOT
    // drained -> next tile's global loads stay in flight across the barrier.
    LGKM0();
    __builtin_amdgcn_s_barrier();
    SBAR0();

    // issue next tile's first A-chunk + B loads, then compute k-step 0
    if (more) { ALOADS0((t + 1) * BK); BLOADS((t + 1) * BK); }
    SBAR0();
    PHASE(0);

    // between phases: issue A-chunk1, store A-chunk0 (reg-dep ~1 phase old)
    if (more) { ALOADS1((t + 1) * BK); ASTORE0(wA); }
    SBAR0();
    PHASE(1);

    // tail: store A-chunk1 (~1 phase old) + B (~2 phases old)
    if (more) { ASTORE1(wA); BSTORE(wB); }
  }

#undef PHASE
#undef ALOADS0
#undef ALOADS1
#undef ASTORE0
#undef ASTORE1
#undef BLOADS
#undef BSTORE

  // ---- epilogue: atomic accumulate (24 blocks collide: 12L x 2K) ----
  // C/D layout (m89-verified): col = lane&15, row = (lane>>4)*4 + j
  const int orow = brow + wrow + ((lane >> 4) << 2);
  const int ocol = ncol + wcol + (lane & 15);
#pragma unroll
  for (int mi = 0; mi < 4; ++mi)
#pragma unroll
    for (int ni = 0; ni < 4; ++ni)
#pragma unroll
      for (int j = 0; j < 4; ++j)
        atomicAdd(out + (size_t)(orow + mi * 16 + j) * ND + (ocol + ni * 16),
                  acc[mi][ni][j]);
}

extern "C" void kernel_launch(void* const* d_in, const int* in_sizes, int n_in,
                              void* d_out, int out_size, void* d_ws, size_t ws_size,
                              hipStream_t stream) {
  const float* acts = (const float*)d_in[0];
  const float* W    = (const float*)d_in[1];
  const float* bias = (const float*)d_in[2];
  const int*   lidx = (const int*)d_in[3];
  float* out = (float*)d_out;

  const int L = in_sizes[0] / (NB * NF);               // 12
  const int nwg = (ND / BN) * (NB / BM) * SPLITK * L;  // 768 = 3 x 256 CUs

  hipFuncSetAttribute((const void*)gemm_kernel,
                      hipFuncAttributeMaxDynamicSharedMemorySize, 2 * BUFBYTES);

  bias_init_kernel<<<dim3((NB * ND + 255) / 256), 256, 0, stream>>>(bias, lidx, out);
  gemm_kernel<<<dim3(nwg), 768, 2 * BUFBYTES, stream>>>(acts, W, lidx, out, nwg);
}

// Round 20
// 468.569 us; speedup vs baseline: 2.0511x; 2.0511x over previous
//
#include <hip/hip_runtime.h>
#include <hip/hip_bf16.h>

#define NB 2048
#define NF 6144
#define ND 768
#define BM 256
#define BN 192
#define BK 64
#define SPLITK 2
#define KCH (NF / SPLITK)  // 3072 per block
#define NTIL (KCH / BK)    // 48 K-tiles per block

// LDS: A 256 rows x 128 B = 32 KB; B 192 rows x 128 B = 24 KB; dbuf = 112 KB
#define ABYTES (BM * 128)
#define BBYTES (BN * 128)
#define BUFBYTES (ABYTES + BBYTES)

typedef __attribute__((ext_vector_type(8))) __bf16 bf16x8;
typedef __attribute__((ext_vector_type(4))) float f32x4;

// Proven layout (0 conflicts across rounds 2-18): 128B rows of 64 bf16,
// 16B-slot 3-bit swizzle slot = (k>>3) ^ (row&7) ^ ((row>>2)&7)
__device__ __forceinline__ char* lds_addr(char* base, int row, int k) {
  const int blk = ((k >> 3) ^ (row & 7) ^ ((row >> 2) & 7)) & 7;
  return base + row * 128 + (blk << 4) + ((k & 7) << 1);
}

#define SBAR0() __builtin_amdgcn_sched_barrier(0)
#define LGKM0()                                            \
  do {                                                     \
    asm volatile("s_waitcnt lgkmcnt(0)" ::: "memory");     \
    SBAR0();                                               \
  } while (0)

// out[b,d] = sum_l bias[l,d]  (clears 0xAA poison deterministically)
__global__ __launch_bounds__(256) void bias_init_kernel(
    const float* __restrict__ bias, const int* __restrict__ lidx,
    float* __restrict__ out) {
  int n = lidx[0] + 1;
  int i = blockIdx.x * 256 + threadIdx.x;
  if (i >= NB * ND) return;
  int d = i % ND;
  float s = 0.f;
  for (int l = 0; l < n; ++l) s += bias[l * ND + d];
  out[i] = s;
}

// FINAL kernel = R8 structure (best measured total: 469-479 us, reproduced
// three times: rounds 8, 16, 18). 256x192 tile, 8 waves (4m x 2n), BK=64,
// split-K x2, LDS double-buffer, ONE lgkm-only barrier per K-tile (global
// loads stay in flight across it), by-fastest XCD decode (FETCH 1.27GB ->
// 405MB), 3 setprio-wrapped MFMA phases per tile.
//
// Design-space map from rounds 9-19 (every alternative measured WORSE):
//  - deeper reg prefetch pipelines spill: any schedule holding staging regs
//    across a barrier exceeds the allocation -> scratch (R3/R15/R17/R19,
//    2-6x slowdowns; WRITE_SIZE balloons 147MB -> 0.7-4.6GB)
//  - extra per-phase barriers cost more than they overlap at 8 lockstep
//    waves (R9, R12); wave-schedule stagger duplicates live ranges (R11)
//  - prepass conversions (A or W^T) pay more HBM tax than they save in-loop
//    (R10 total 637, R13 total 543, R14 total 498 vs this 469)
//  - sub-128B-row LDS write patterns reintroduce bank conflicts (R5, R12,
//    R19); only this 128B-row 3-bit-XOR layout measured 0 conflicts
__global__ __launch_bounds__(512, 2) void gemm_kernel(
    const float* __restrict__ acts, const float* __restrict__ W,
    const int* __restrict__ lidx, float* __restrict__ out, int nwg) {
  extern __shared__ char cbuf[];  // 2 * BUFBYTES

  const int chunk = nwg >> 3;  // 96
  const int swz = (blockIdx.x & 7) * chunk + (blockIdx.x >> 3);
  const int by = swz & 3;  // id = by + 4*(m + 8*(ks + 2*l))
  int rem = swz >> 2;
  const int m = rem & 7; rem >>= 3;
  const int ks = rem & 1; rem >>= 1;
  const int l = rem;
  if (l > lidx[0]) return;  // uniform exit before any barrier

  const int brow = m * BM;
  const int ncol = by * BN;
  const int k0 = ks * KCH;

  const int tid = threadIdx.x;
  const int lane = tid & 63;
  const int wid = tid >> 6;          // 8 waves: 4m x 2n
  const int wrow = (wid >> 1) * 64;  // 0,64,128,192
  const int wcol = (wid & 1) * 96;   // 0,96

  f32x4 acc[4][6];
#pragma unroll
  for (int i = 0; i < 4; ++i)
#pragma unroll
    for (int j = 0; j < 6; ++j) acc[i][j] = (f32x4){0.f, 0.f, 0.f, 0.f};

  // A staging: thread -> (row = tid>>3 (+64 per pass p<4), 8 consecutive k)
  const int s_arow = tid >> 3;
  const int s_ak = (tid & 7) * 8;
  // B staging: threads 0..383: (4 consecutive d, 8 consecutive k)
  const bool bstage = tid < 384;
  const int s_bd = (tid % 48) * 4;
  const int s_bk = (tid / 48) * 8;

  const float* Aptr =
      acts + (size_t)l * NB * NF + (size_t)(brow + s_arow) * NF + k0 + s_ak;
  const float* Bptr =
      W + (size_t)l * NF * ND + (size_t)(k0 + s_bk) * ND + (ncol + s_bd);

  float4 av[4][2];  // A: 4 row-passes x 8 k (32 VGPR)
  float4 bv[8];     // B: 8 k-rows x 4 d   (32 VGPR, waves 0-5)

  auto LOADS = [&](int kb) {
#pragma unroll
    for (int p = 0; p < 4; ++p) {
      av[p][0] = *(const float4*)(Aptr + (size_t)(64 * p) * NF + kb);
      av[p][1] = *(const float4*)(Aptr + (size_t)(64 * p) * NF + kb + 4);
    }
    if (bstage) {
#pragma unroll
      for (int j = 0; j < 8; ++j)
        bv[j] = *(const float4*)(Bptr + (size_t)(kb + j) * ND);
    }
  };

  auto STORE = [&](char* cA_, char* cB_) {
#pragma unroll
    for (int p = 0; p < 4; ++p) {
      bf16x8 h;
      h[0] = (__bf16)av[p][0].x; h[1] = (__bf16)av[p][0].y;
      h[2] = (__bf16)av[p][0].z; h[3] = (__bf16)av[p][0].w;
      h[4] = (__bf16)av[p][1].x; h[5] = (__bf16)av[p][1].y;
      h[6] = (__bf16)av[p][1].z; h[7] = (__bf16)av[p][1].w;
      *(bf16x8*)lds_addr(cA_, s_arow + 64 * p, s_ak) = h;
    }
    if (bstage) {
#pragma unroll
      for (int dd = 0; dd < 4; ++dd) {
        bf16x8 h;
#pragma unroll
        for (int j = 0; j < 8; ++j) h[j] = (__bf16)bv[j][dd];
        *(bf16x8*)lds_addr(cB_, s_bd + dd, s_bk) = h;
      }
    }
  };

  // ---- prologue: tile 0 staged into buf0 (self-waiting, once) ----
  LOADS(0);
  STORE(cbuf, cbuf + ABYTES);

  for (int t = 0; t < NTIL; ++t) {
    const int cur = t & 1;
    char* rA = cbuf + (size_t)cur * BUFBYTES;
    char* rB = rA + ABYTES;
    char* wA = cbuf + (size_t)(cur ^ 1) * BUFBYTES;
    char* wB = wA + ABYTES;

    // tile boundary: writes visible + reads done (lgkm drain); vmcnt NOT
    // drained -> next tile's global loads stay in flight across the barrier.
    LGKM0();
    __builtin_amdgcn_s_barrier();
    SBAR0();

    if (t + 1 < NTIL) LOADS((t + 1) * BK);  // consumed after 3 MFMA phases
    SBAR0();

    // A fragments for all 3 phases (read once, 32 VGPR)
    bf16x8 aF[4][2];
#pragma unroll
    for (int mi = 0; mi < 4; ++mi)
#pragma unroll
      for (int s = 0; s < 2; ++s)
        aF[mi][s] = *(const bf16x8*)lds_addr(
            rA, wrow + mi * 16 + (lane & 15), s * 32 + (lane >> 4) * 8);

    // 3 phases: each reads one B n-pair, then a 16-MFMA cluster
#pragma unroll
    for (int p = 0; p < 3; ++p) {
      bf16x8 bF[2][2];
#pragma unroll
      for (int ni = 0; ni < 2; ++ni)
#pragma unroll
        for (int s = 0; s < 2; ++s)
          bF[ni][s] = *(const bf16x8*)lds_addr(
              rB, wcol + (2 * p + ni) * 16 + (lane & 15),
              s * 32 + (lane >> 4) * 8);
      LGKM0();
      __builtin_amdgcn_s_setprio(1);
#pragma unroll
      for (int s = 0; s < 2; ++s)
#pragma unroll
        for (int mi = 0; mi < 4; ++mi)
#pragma unroll
          for (int ni = 0; ni < 2; ++ni)
            acc[mi][2 * p + ni] = __builtin_amdgcn_mfma_f32_16x16x32_bf16(
                aF[mi][s], bF[ni][s], acc[mi][2 * p + ni], 0, 0, 0);
      __builtin_amdgcn_s_setprio(0);
      SBAR0();
    }

    // cvt+write next tile (reg-dep vmcnt wait; loads are ~3 phases old)
    if (t + 1 < NTIL) STORE(wA, wB);
  }

  // ---- epilogue: atomic accumulate (24 blocks collide: 12L x 2K) ----
  // C/D layout (m89-verified): col = lane&15, row = (lane>>4)*4 + j
  const int orow = brow + wrow + ((lane >> 4) << 2);
  const int ocol = ncol + wcol + (lane & 15);
#pragma unroll
  for (int mi = 0; mi < 4; ++mi)
#pragma unroll
    for (int ni = 0; ni < 6; ++ni)
#pragma unroll
      for (int j = 0; j < 4; ++j)
        atomicAdd(out + (size_t)(orow + mi * 16 + j) * ND + (ocol + ni * 16),
                  acc[mi][ni][j]);
}

extern "C" void kernel_launch(void* const* d_in, const int* in_sizes, int n_in,
                              void* d_out, int out_size, void* d_ws, size_t ws_size,
                              hipStream_t stream) {
  const float* acts = (const float*)d_in[0];
  const float* W    = (const float*)d_in[1];
  const float* bias = (const float*)d_in[2];
  const int*   lidx = (const int*)d_in[3];
  float* out = (float*)d_out;

  const int L = in_sizes[0] / (NB * NF);               // 12
  const int nwg = (ND / BN) * (NB / BM) * SPLITK * L;  // 768 = 3 x 256 CUs

  hipFuncSetAttribute((const void*)gemm_kernel,
                      hipFuncAttributeMaxDynamicSharedMemorySize, 2 * BUFBYTES);

  bias_init_kernel<<<dim3((NB * ND + 255) / 256), 256, 0, stream>>>(bias, lidx, out);
  gemm_kernel<<<dim3(nwg), 512, 2 * BUFBYTES, stream>>>(acts, W, lidx, out, nwg);
}